// Round 10
// baseline (140.537 us; speedup 1.0000x reference)
//
#include <hip/hip_runtime.h>

typedef unsigned short u16;
typedef unsigned int u32;
typedef __attribute__((ext_vector_type(8))) __bf16 bf16x8;
typedef __attribute__((ext_vector_type(8))) unsigned short u16x8;
typedef __attribute__((ext_vector_type(2))) unsigned int u32x2;
typedef __attribute__((ext_vector_type(4))) float f32x4;

// ---- bf16 <-> f32 (RNE), bit-exact storage as u16 ----
__device__ __forceinline__ u16 f2bf(float f) {
  u32 u = __builtin_bit_cast(u32, f);
  u += 0x7FFFu + ((u >> 16) & 1u);
  return (u16)(u >> 16);
}
__device__ __forceinline__ float bf2f(u16 h) {
  u32 u = ((u32)h) << 16;
  return __builtin_bit_cast(float, u);
}

// in-register butterfly set over 16 elements, pair mask M (k3 only)
template <int M>
__device__ __forceinline__ void bfly16(float r[16]) {
#pragma unroll
  for (int j = 0; j < 16; ++j)
    if ((j & M) == 0) {
      float a = r[j], b = r[j | M];
      r[j] = a + b;
      r[j | M] = a - b;
    }
}

// ---- K0: conv_w fp32 -> bf16 in MFMA-fragment-major order:
//      wc[frag_id*512 + lane*8 + j], frag_id = ((fp*4+wv)*2+fm)*4+q ----
__global__ __launch_bounds__(256) void k0_wcat(const float* __restrict__ cw,
                                               u16* __restrict__ wc) {
  const int i = blockIdx.x * 256 + threadIdx.x;  // 0..32767
  const int j = i & 7;
  const int lr = (i >> 3) & 15;
  const int lq = (i >> 7) & 3;
  const int q = (i >> 9) & 3;
  const int fm = (i >> 11) & 1;
  const int wv = (i >> 12) & 3;
  const int fp = (i >> 14) & 1;
  const int row = fp * 128 + wv * 32 + fm * 16 + lr;  // p*128 + o
  const int k = q * 32 + lq * 8 + j;
  wc[i] = f2bf(cw[row * 128 + k]);
}

// ---- K1 (MFMA WHT): wave = one (b,c) plane; f2_plane = H64 . Xb . H64.
//      GEMM1: C1 = Xb*H (A = x from global, B = H via popcount, in-reg).
//      C1^T staged bf16 in wave-private LDS (no barriers).
//      GEMM2: f2 = H*C1 (A = same H frags, B = c1t b128 reads).
//      LDS REUSE: after cb-frags are in registers, c1t doubles as the
//      [pos][c8] output staging (barrier-fenced) -> 73.7KB total, 2 blk/CU ----
__global__ __launch_bounds__(512, 4) void k1_fwht(const float* __restrict__ x,
                                                  u16* __restrict__ f2) {
  __shared__ u16 c1t[8][64 * 72];  // per-wave C1^T; reused as out staging
  const int t = threadIdx.x;
  const int p = t >> 6;  // wave = plane within c8 group
  const int l = t & 63, lr = l & 15, lq = l >> 4;
  const int b = blockIdx.x >> 4, cg = blockIdx.x & 15;
  const float* xp = x + (size_t)(b * 128 + cg * 8 + p) * 3136;

  // H fragments (A-frag == B-frag by symmetry): hf[tile][q][j] =
  // H[16*tile+lr][32q+8lq+j] = parity ? -1 : +1 (bf16 bits directly)
  u16x8 hf[4][2];
#pragma unroll
  for (int tl = 0; tl < 4; ++tl)
#pragma unroll
    for (int q = 0; q < 2; ++q)
#pragma unroll
      for (int j = 0; j < 8; ++j) {
        const int kk = 32 * q + 8 * lq + j;
        const int rr = 16 * tl + lr;
        hf[tl][q][j] = (__builtin_popcount(kk & rr) & 1) ? 0xBF80u : 0x3F80u;
      }

  // load all X fragments upfront (16 dwordx4, full MLP, full-line coalesced)
  float4 xlo[4][2], xhi[4][2];
#pragma unroll
  for (int m = 0; m < 4; ++m)
#pragma unroll
    for (int q = 0; q < 2; ++q) {
      const int h = m * 16 + lr;
      const int w0 = 32 * q + 8 * lq;
      float4 a = make_float4(0.f, 0.f, 0.f, 0.f);
      float4 c = make_float4(0.f, 0.f, 0.f, 0.f);
      if (h < 56 && w0 < 56) {
        a = *(const float4*)(xp + h * 56 + w0);
        c = *(const float4*)(xp + h * 56 + w0 + 4);
      }
      xlo[m][q] = a;
      xhi[m][q] = c;
    }
  // convert to bf16 A-fragments (row=h, k=w)
  bf16x8 ax[4][2];
#pragma unroll
  for (int m = 0; m < 4; ++m)
#pragma unroll
    for (int q = 0; q < 2; ++q) {
      u16x8 v;
      v[0] = f2bf(xlo[m][q].x); v[1] = f2bf(xlo[m][q].y);
      v[2] = f2bf(xlo[m][q].z); v[3] = f2bf(xlo[m][q].w);
      v[4] = f2bf(xhi[m][q].x); v[5] = f2bf(xhi[m][q].y);
      v[6] = f2bf(xhi[m][q].z); v[7] = f2bf(xhi[m][q].w);
      ax[m][q] = __builtin_bit_cast(bf16x8, v);
    }

  // GEMM1: C1[h][w'] = sum_w Xb[h][w] H[w][w']
  f32x4 acc1[4][4] = {};
#pragma unroll
  for (int q = 0; q < 2; ++q)
#pragma unroll
    for (int m = 0; m < 4; ++m)
#pragma unroll
      for (int n = 0; n < 4; ++n)
        acc1[m][n] = __builtin_amdgcn_mfma_f32_16x16x32_bf16(
            ax[m][q], __builtin_bit_cast(bf16x8, hf[n][q]), acc1[m][n], 0, 0, 0);

  // stage C1^T (bf16): lane holds h = m*16+4*lq+r (r=0..3), w' = n*16+lr
  u16* cwv = &c1t[p][0];
#pragma unroll
  for (int m = 0; m < 4; ++m)
#pragma unroll
    for (int n = 0; n < 4; ++n) {
      u32x2 pk;
      pk[0] = (u32)f2bf(acc1[m][n][0]) | ((u32)f2bf(acc1[m][n][1]) << 16);
      pk[1] = (u32)f2bf(acc1[m][n][2]) | ((u32)f2bf(acc1[m][n][3]) << 16);
      *(u32x2*)&cwv[(n * 16 + lr) * 72 + m * 16 + 4 * lq] = pk;
    }
  // wave-private LDS: compiler inserts lgkmcnt waits; no barrier needed.

  // GEMM2 B-frags: col = w = n*16+lr, k = h = 32q+8lq+j -> b128 from c1t
  bf16x8 cb[4][2];
#pragma unroll
  for (int n = 0; n < 4; ++n)
#pragma unroll
    for (int q = 0; q < 2; ++q)
      cb[n][q] = __builtin_bit_cast(
          bf16x8, *(const u16x8*)&cwv[(n * 16 + lr) * 72 + 32 * q + 8 * lq]);

  // all waves' cb reads are in registers past this barrier (lgkmcnt drained)
  __syncthreads();

  // GEMM2: f2[h'][w] = sum_h H[h'][h] C1[h][w]
  f32x4 acc2[4][4] = {};
#pragma unroll
  for (int q = 0; q < 2; ++q)
#pragma unroll
    for (int m = 0; m < 4; ++m)
#pragma unroll
      for (int n = 0; n < 4; ++n)
        acc2[m][n] = __builtin_amdgcn_mfma_f32_16x16x32_bf16(
            __builtin_bit_cast(bf16x8, hf[m][q]), cb[n][q], acc2[m][n], 0, 0, 0);

  // scatter into [pos][c8] staging (REUSED c1t memory):
  // pos = (m*16+4lq+r)*64 + n*16+lr
  u16* ostg = &c1t[0][0];
#pragma unroll
  for (int m = 0; m < 4; ++m)
#pragma unroll
    for (int n = 0; n < 4; ++n)
#pragma unroll
      for (int r = 0; r < 4; ++r) {
        const int pos = (m * 16 + 4 * lq + r) * 64 + n * 16 + lr;
        ostg[pos * 8 + p] = f2bf(acc2[m][n][r]);
      }
  __syncthreads();

  // cooperative readout: 16B/lane contiguous -> 8KB per block-instr
  u16* dst = f2 + ((size_t)(b * 16 + cg) << 15);
#pragma unroll
  for (int k = 0; k < 8; ++k) {
    const int g = k * 512 + t;  // pos
    *(u16x8*)(dst + (size_t)g * 8) = *(const u16x8*)&ostg[g * 8];
  }
}

// ---- K2: per (b, 64-pos tile): GEMM from global (no LDS) + v-scale +
//          soft-threshold + p-sum, IN-PLACE: f2[b][cg][pos][c8] -> [b][og][pos][o8]
//          Full register prefetch of all A/B fragments for MLP. ----
__global__ __launch_bounds__(256, 2) void k2_mix(u16* __restrict__ fg,
                                                 const u16* __restrict__ wc,
                                                 const float* __restrict__ vv,
                                                 const float* __restrict__ tt) {
  const int t = threadIdx.x;
  const int b = blockIdx.x >> 6;
  const int p0 = (blockIdx.x & 63) << 6;
  u16* fb = fg + ((size_t)b << 19);
  const int wv = t >> 6, l = t & 63, lr = l & 15, lq = l >> 4;

  // ---- prefetch ALL B-fragments (LLC/HBM latency) ----
  bf16x8 bfr[4][4];  // [q][fn]
#pragma unroll
  for (int q = 0; q < 4; ++q)
#pragma unroll
    for (int fn = 0; fn < 4; ++fn)
      bfr[q][fn] = __builtin_bit_cast(
          bf16x8, *(const u16x8*)(fb + ((size_t)(4 * q + lq) << 15) +
                                  (size_t)(p0 + fn * 16 + lr) * 8));
  // ---- prefetch ALL A-fragments (fragment-major wcat: 1KB contiguous/instr) ----
  bf16x8 afr[4][2][2];  // [q][fp][fm]
#pragma unroll
  for (int q = 0; q < 4; ++q)
#pragma unroll
    for (int fp = 0; fp < 2; ++fp)
#pragma unroll
      for (int fm = 0; fm < 2; ++fm) {
        const int frag_id = ((fp * 4 + wv) * 2 + fm) * 4 + q;
        afr[q][fp][fm] = __builtin_bit_cast(
            bf16x8, *(const u16x8*)(wc + (frag_id << 9) + l * 8));
      }
  // ---- epilogue scalars, loaded before the hazard barrier ----
  float v0s[4], v1s[4], t0s[4], t1s[4];
#pragma unroll
  for (int fn = 0; fn < 4; ++fn) {
    const int pos = p0 + fn * 16 + lr;
    v0s[fn] = vv[pos];
    v1s[fn] = vv[4096 + pos];
    t0s[fn] = fmaxf(tt[pos], 0.f);
    t1s[fn] = fmaxf(tt[4096 + pos], 0.f);
  }

  f32x4 acc[2][2][4] = {};  // [fp][fm][fn]
#pragma unroll
  for (int q = 0; q < 4; ++q)
#pragma unroll
    for (int fn = 0; fn < 4; ++fn)
#pragma unroll
      for (int fp = 0; fp < 2; ++fp)
#pragma unroll
        for (int fm = 0; fm < 2; ++fm)
          acc[fp][fm][fn] = __builtin_amdgcn_mfma_f32_16x16x32_bf16(
              afr[q][fp][fm], bfr[q][fn], acc[fp][fm][fn], 0, 0, 0);

  // all waves' reads of this tile drained (vmcnt(0) at barrier) before stores
  __syncthreads();
  // epilogue: v-scale, soft-threshold, p-sum (in-register), b64 stores
#pragma unroll
  for (int fn = 0; fn < 4; ++fn) {
    const int pos = p0 + fn * 16 + lr;  // D col = lane&15
#pragma unroll
    for (int fm = 0; fm < 2; ++fm) {
      u16 w[4];
#pragma unroll
      for (int rg = 0; rg < 4; ++rg) {  // D row = 4*lq+rg -> o = wv*32+fm*16+lq*4+rg
        const float z0 = v0s[fn] * acc[0][fm][fn][rg];
        const float z1 = v1s[fn] * acc[1][fm][fn][rg];
        const float s0v = copysignf(fmaxf(fabsf(z0) - t0s[fn], 0.f), z0);
        const float s1v = copysignf(fmaxf(fabsf(z1) - t1s[fn], 0.f), z1);
        w[rg] = f2bf(s0v + s1v);
      }
      const int og = wv * 4 + fm * 2 + (lq >> 1);  // o>>3
      u32x2 pk;
      pk[0] = (u32)w[0] | ((u32)w[1] << 16);
      pk[1] = (u32)w[2] | ((u32)w[3] << 16);
      *(u32x2*)(fb + ((size_t)og << 15) + (size_t)pos * 8 + (lq & 1) * 4) = pk;
    }
  }
}

// ---- K3: block = (b, og): 8-plane 2D IWHT (x 1/4096) + crop + residual;
//          reads g[b][og][pos][o8] -> 256B contiguous per thread ----
__global__ __launch_bounds__(256) void k3_iwht(const u16* __restrict__ g,
                                               const float* __restrict__ x,
                                               float* __restrict__ y) {
  __shared__ float lds[64 * 68];
  const int t = threadIdx.x;
  const int b = blockIdx.x >> 4;
  const int og = blockIdx.x & 15;
  const u16* gb = g + ((size_t)(b * 16 + og) << 15);
  const int hA = t >> 2, wq = t & 3;
  const int hg = t >> 4, rB = t & 15;
  const int wC = t & 63, rr = t >> 6;
  // preload phase-A ownership for all 8 planes: 16 b128 loads, 256B contiguous
  u16x8 inv[16];
#pragma unroll
  for (int e = 0; e < 16; ++e)
    inv[e] = *(const u16x8*)(gb + (size_t)(hA * 64 + wq * 16 + e) * 8);

#pragma unroll
  for (int pp = 0; pp < 8; ++pp) {
    float r[16];
#pragma unroll
    for (int e = 0; e < 16; ++e) r[e] = bf2f(inv[e][pp]);
    bfly16<1>(r); bfly16<2>(r); bfly16<4>(r); bfly16<8>(r);
    if (pp) __syncthreads();
#pragma unroll
    for (int c4 = 0; c4 < 4; ++c4)
      *(float4*)&lds[hA * 68 + wq * 16 + c4 * 4] =
          make_float4(r[c4 * 4 + 0], r[c4 * 4 + 1], r[c4 * 4 + 2], r[c4 * 4 + 3]);
    __syncthreads();
    float q[16];
#pragma unroll
    for (int k = 0; k < 4; ++k)
#pragma unroll
      for (int d = 0; d < 4; ++d)
        q[k * 4 + d] = lds[(hg * 4 + d) * 68 + k * 16 + rB];
    bfly16<4>(q); bfly16<8>(q); bfly16<1>(q); bfly16<2>(q);
#pragma unroll
    for (int k = 0; k < 4; ++k)
#pragma unroll
      for (int d = 0; d < 4; ++d)
        lds[(hg * 4 + d) * 68 + k * 16 + rB] = q[k * 4 + d];
    __syncthreads();
    float s[16];
#pragma unroll
    for (int j = 0; j < 16; ++j) s[j] = lds[(4 * j + rr) * 68 + wC];
    bfly16<1>(s); bfly16<2>(s); bfly16<4>(s); bfly16<8>(s);
    if (wC < 56) {
      const size_t plane = (size_t)(b * 128 + og * 8 + pp) * 3136;
#pragma unroll
      for (int j = 0; j < 14; ++j) {  // h = 4j+rr <= 55
        const int h = 4 * j + rr;
        const size_t idx = plane + (size_t)(h * 56 + wC);
        y[idx] = x[idx] + s[j] * (1.f / 4096.f);
      }
    }
  }
}

extern "C" void kernel_launch(void* const* d_in, const int* in_sizes, int n_in,
                              void* d_out, int out_size, void* d_ws, size_t ws_size,
                              hipStream_t stream) {
  const float* x = (const float*)d_in[0];
  const float* cw = (const float*)d_in[1];
  const float* v = (const float*)d_in[2];
  const float* T = (const float*)d_in[3];
  float* y = (float*)d_out;

  u16* f2 = (u16*)d_ws;                        // 64*16*4096*8 bf16 = 67,108,864 B
  u16* wcat = (u16*)((char*)d_ws + 67108864);  // 2*128*128 bf16 = 65,536 B

  k0_wcat<<<128, 256, 0, stream>>>(cw, wcat);
  k1_fwht<<<1024, 512, 0, stream>>>(x, f2);
  k2_mix<<<4096, 256, 0, stream>>>(f2, wcat, v, T);
  k3_iwht<<<1024, 256, 0, stream>>>(f2, x, y);
}

// Round 11
// 125.912 us; speedup vs baseline: 1.1161x; 1.1161x over previous
//
#include <hip/hip_runtime.h>

typedef unsigned short u16;
typedef unsigned int u32;
typedef __attribute__((ext_vector_type(8))) __bf16 bf16x8;
typedef __attribute__((ext_vector_type(8))) unsigned short u16x8;
typedef __attribute__((ext_vector_type(2))) unsigned int u32x2;
typedef __attribute__((ext_vector_type(4))) float f32x4;

// ---- bf16 <-> f32 (RNE), bit-exact storage as u16 ----
__device__ __forceinline__ u16 f2bf(float f) {
  u32 u = __builtin_bit_cast(u32, f);
  u += 0x7FFFu + ((u >> 16) & 1u);
  return (u16)(u >> 16);
}
__device__ __forceinline__ float bf2f(u16 h) {
  u32 u = ((u32)h) << 16;
  return __builtin_bit_cast(float, u);
}

// LDS-only barrier: drains LDS ops, leaves global loads in flight
// (avoids hipcc's s_waitcnt vmcnt(0) drain at __syncthreads()).
__device__ __forceinline__ void lds_barrier() {
  asm volatile("s_waitcnt lgkmcnt(0)" ::: "memory");
  __builtin_amdgcn_s_barrier();
}

// in-register butterfly set over 16 elements, pair mask M
template <int M>
__device__ __forceinline__ void bfly16(float r[16]) {
#pragma unroll
  for (int j = 0; j < 16; ++j)
    if ((j & M) == 0) {
      float a = r[j], b = r[j | M];
      r[j] = a + b;
      r[j | M] = a - b;
    }
}

// ---- K0: conv_w fp32 -> bf16 in MFMA-fragment-major order:
//      wc[frag_id*512 + lane*8 + j], frag_id = ((fp*4+wv)*2+fm)*4+q ----
__global__ __launch_bounds__(256) void k0_wcat(const float* __restrict__ cw,
                                               u16* __restrict__ wc) {
  const int i = blockIdx.x * 256 + threadIdx.x;  // 0..32767
  const int j = i & 7;
  const int lr = (i >> 3) & 15;
  const int lq = (i >> 7) & 3;
  const int q = (i >> 9) & 3;
  const int fm = (i >> 11) & 1;
  const int wv = (i >> 12) & 3;
  const int fp = (i >> 14) & 1;
  const int row = fp * 128 + wv * 32 + fm * 16 + lr;  // p*128 + o
  const int k = q * 32 + lq * 8 + j;
  wc[i] = f2bf(cw[row * 128 + k]);
}

// ---- K1: block = (b, cg): pad + 2D FWHT on 8 channel planes.
//      Round-6 structure + 1-plane load prefetch + non-draining barriers +
//      ping-pong LDS. __launch_bounds__(256,2): 256-VGPR cap, NO spills
//      (round-7's failure was the (256,4) 128-reg cap spilling ~140 live).
//      Writes f2[b][cg16][pos][c8] (contiguous 1KB/wave stores). ----
__global__ __launch_bounds__(256, 2) void k1_fwht(const float* __restrict__ x,
                                                  u16* __restrict__ f2) {
  __shared__ float lds[2][64 * 68];  // ping-pong, padded stride 68
  const int t = threadIdx.x;
  const int b = blockIdx.x >> 4;
  const int cg = blockIdx.x & 15;
  const int hA = t >> 2, wq = t & 3;   // phase A ownership
  const int hg = t >> 4, rB = t & 15;  // phase B ownership
  const int wC = t & 63, rr = t >> 6;  // phase C ownership
  const bool hok = hA < 56;
  const float* xbase = x + (size_t)(b * 128 + cg * 8) * 3136;
  float4 ld0[4], ld1[4];  // double-buffered input rows (named: static idx)
  u16x8 outv[16];         // [j][plane]

  // prefetch plane 0 into ld0
#pragma unroll
  for (int c4 = 0; c4 < 4; ++c4) {
    const int w0 = wq * 16 + c4 * 4;
    float4 v4 = make_float4(0.f, 0.f, 0.f, 0.f);
    if (hok && w0 < 56) v4 = *(const float4*)(xbase + hA * 56 + w0);
    ld0[c4] = v4;
  }

#pragma unroll
  for (int pp = 0; pp < 8; ++pp) {
    // issue next plane's loads FIRST; they stay in flight through barriers
    if (pp < 7) {
      const float* xp = xbase + (size_t)(pp + 1) * 3136;
#pragma unroll
      for (int c4 = 0; c4 < 4; ++c4) {
        const int w0 = wq * 16 + c4 * 4;
        float4 v4 = make_float4(0.f, 0.f, 0.f, 0.f);
        if (hok && w0 < 56) v4 = *(const float4*)(xp + hA * 56 + w0);
        if (pp & 1) ld0[c4] = v4; else ld1[c4] = v4;
      }
    }
    float r[16];
#pragma unroll
    for (int c4 = 0; c4 < 4; ++c4) {
      const float4 v4 = (pp & 1) ? ld1[c4] : ld0[c4];
      r[c4 * 4 + 0] = v4.x; r[c4 * 4 + 1] = v4.y;
      r[c4 * 4 + 2] = v4.z; r[c4 * 4 + 3] = v4.w;
    }
    bfly16<1>(r); bfly16<2>(r); bfly16<4>(r); bfly16<8>(r);  // w 1,2,4,8
#pragma unroll
    for (int c4 = 0; c4 < 4; ++c4)
      *(float4*)&lds[pp & 1][hA * 68 + wq * 16 + c4 * 4] =
          make_float4(r[c4 * 4 + 0], r[c4 * 4 + 1], r[c4 * 4 + 2], r[c4 * 4 + 3]);
    lds_barrier();
    // phase B: w stages 16,32 + h stages 1,2
    float q[16];
#pragma unroll
    for (int k = 0; k < 4; ++k)
#pragma unroll
      for (int d = 0; d < 4; ++d)
        q[k * 4 + d] = lds[pp & 1][(hg * 4 + d) * 68 + k * 16 + rB];
    bfly16<4>(q); bfly16<8>(q); bfly16<1>(q); bfly16<2>(q);
#pragma unroll
    for (int k = 0; k < 4; ++k)
#pragma unroll
      for (int d = 0; d < 4; ++d)
        lds[pp & 1][(hg * 4 + d) * 68 + k * 16 + rB] = q[k * 4 + d];  // own addrs
    lds_barrier();
    // phase C: h stages 4,8,16,32
    float s[16];
#pragma unroll
    for (int j = 0; j < 16; ++j) s[j] = lds[pp & 1][(4 * j + rr) * 68 + wC];
    bfly16<1>(s); bfly16<2>(s); bfly16<4>(s); bfly16<8>(s);
#pragma unroll
    for (int j = 0; j < 16; ++j) outv[j][pp] = f2bf(s[j]);
    // no trailing barrier: plane pp+1 uses the other buffer; reuse of this
    // buffer (plane pp+2's store) is fenced by plane pp+1's two barriers.
  }
  // f2[b][cg][pos][c8]: lane stores 16B at pos*16B, wC consecutive -> 1KB/instr
  u16* dst = f2 + ((size_t)(b * 16 + cg) << 15);
#pragma unroll
  for (int j = 0; j < 16; ++j) {
    const int pos = (4 * j + rr) * 64 + wC;
    *(u16x8*)(dst + (size_t)pos * 8) = outv[j];
  }
}

// ---- K2: per (b, 64-pos tile): GEMM from global (no LDS) + v-scale +
//          soft-threshold + p-sum, IN-PLACE: f2[b][cg][pos][c8] -> [b][og][pos][o8]
//          Full register prefetch of all A/B fragments for MLP. ----
__global__ __launch_bounds__(256, 2) void k2_mix(u16* __restrict__ fg,
                                                 const u16* __restrict__ wc,
                                                 const float* __restrict__ vv,
                                                 const float* __restrict__ tt) {
  const int t = threadIdx.x;
  const int b = blockIdx.x >> 6;
  const int p0 = (blockIdx.x & 63) << 6;
  u16* fb = fg + ((size_t)b << 19);
  const int wv = t >> 6, l = t & 63, lr = l & 15, lq = l >> 4;

  // ---- prefetch ALL B-fragments (LLC/HBM latency) ----
  bf16x8 bfr[4][4];  // [q][fn]
#pragma unroll
  for (int q = 0; q < 4; ++q)
#pragma unroll
    for (int fn = 0; fn < 4; ++fn)
      bfr[q][fn] = __builtin_bit_cast(
          bf16x8, *(const u16x8*)(fb + ((size_t)(4 * q + lq) << 15) +
                                  (size_t)(p0 + fn * 16 + lr) * 8));
  // ---- prefetch ALL A-fragments (fragment-major wcat: 1KB contiguous/instr) ----
  bf16x8 afr[4][2][2];  // [q][fp][fm]
#pragma unroll
  for (int q = 0; q < 4; ++q)
#pragma unroll
    for (int fp = 0; fp < 2; ++fp)
#pragma unroll
      for (int fm = 0; fm < 2; ++fm) {
        const int frag_id = ((fp * 4 + wv) * 2 + fm) * 4 + q;
        afr[q][fp][fm] = __builtin_bit_cast(
            bf16x8, *(const u16x8*)(wc + (frag_id << 9) + l * 8));
      }
  // ---- epilogue scalars, loaded before the hazard barrier ----
  float v0s[4], v1s[4], t0s[4], t1s[4];
#pragma unroll
  for (int fn = 0; fn < 4; ++fn) {
    const int pos = p0 + fn * 16 + lr;
    v0s[fn] = vv[pos];
    v1s[fn] = vv[4096 + pos];
    t0s[fn] = fmaxf(tt[pos], 0.f);
    t1s[fn] = fmaxf(tt[4096 + pos], 0.f);
  }

  f32x4 acc[2][2][4] = {};  // [fp][fm][fn]
#pragma unroll
  for (int q = 0; q < 4; ++q)
#pragma unroll
    for (int fn = 0; fn < 4; ++fn)
#pragma unroll
      for (int fp = 0; fp < 2; ++fp)
#pragma unroll
        for (int fm = 0; fm < 2; ++fm)
          acc[fp][fm][fn] = __builtin_amdgcn_mfma_f32_16x16x32_bf16(
              afr[q][fp][fm], bfr[q][fn], acc[fp][fm][fn], 0, 0, 0);

  // all waves' reads of this tile drained (vmcnt(0) at barrier) before stores
  __syncthreads();
  // epilogue: v-scale, soft-threshold, p-sum (in-register), b64 stores
#pragma unroll
  for (int fn = 0; fn < 4; ++fn) {
    const int pos = p0 + fn * 16 + lr;  // D col = lane&15
#pragma unroll
    for (int fm = 0; fm < 2; ++fm) {
      u16 w[4];
#pragma unroll
      for (int rg = 0; rg < 4; ++rg) {  // D row = 4*lq+rg -> o = wv*32+fm*16+lq*4+rg
        const float z0 = v0s[fn] * acc[0][fm][fn][rg];
        const float z1 = v1s[fn] * acc[1][fm][fn][rg];
        const float s0v = copysignf(fmaxf(fabsf(z0) - t0s[fn], 0.f), z0);
        const float s1v = copysignf(fmaxf(fabsf(z1) - t1s[fn], 0.f), z1);
        w[rg] = f2bf(s0v + s1v);
      }
      const int og = wv * 4 + fm * 2 + (lq >> 1);  // o>>3
      u32x2 pk;
      pk[0] = (u32)w[0] | ((u32)w[1] << 16);
      pk[1] = (u32)w[2] | ((u32)w[3] << 16);
      *(u32x2*)(fb + ((size_t)og << 15) + (size_t)pos * 8 + (lq & 1) * 4) = pk;
    }
  }
}

// ---- K3: block = (b, og): 8-plane 2D IWHT (x 1/4096) + crop + residual;
//          reads g[b][og][pos][o8] -> 256B contiguous per thread ----
__global__ __launch_bounds__(256) void k3_iwht(const u16* __restrict__ g,
                                               const float* __restrict__ x,
                                               float* __restrict__ y) {
  __shared__ float lds[64 * 68];
  const int t = threadIdx.x;
  const int b = blockIdx.x >> 4;
  const int og = blockIdx.x & 15;
  const u16* gb = g + ((size_t)(b * 16 + og) << 15);
  const int hA = t >> 2, wq = t & 3;
  const int hg = t >> 4, rB = t & 15;
  const int wC = t & 63, rr = t >> 6;
  // preload phase-A ownership for all 8 planes: 16 b128 loads, 256B contiguous
  u16x8 inv[16];
#pragma unroll
  for (int e = 0; e < 16; ++e)
    inv[e] = *(const u16x8*)(gb + (size_t)(hA * 64 + wq * 16 + e) * 8);

#pragma unroll
  for (int pp = 0; pp < 8; ++pp) {
    float r[16];
#pragma unroll
    for (int e = 0; e < 16; ++e) r[e] = bf2f(inv[e][pp]);
    bfly16<1>(r); bfly16<2>(r); bfly16<4>(r); bfly16<8>(r);
    if (pp) __syncthreads();
#pragma unroll
    for (int c4 = 0; c4 < 4; ++c4)
      *(float4*)&lds[hA * 68 + wq * 16 + c4 * 4] =
          make_float4(r[c4 * 4 + 0], r[c4 * 4 + 1], r[c4 * 4 + 2], r[c4 * 4 + 3]);
    __syncthreads();
    float q[16];
#pragma unroll
    for (int k = 0; k < 4; ++k)
#pragma unroll
      for (int d = 0; d < 4; ++d)
        q[k * 4 + d] = lds[(hg * 4 + d) * 68 + k * 16 + rB];
    bfly16<4>(q); bfly16<8>(q); bfly16<1>(q); bfly16<2>(q);
#pragma unroll
    for (int k = 0; k < 4; ++k)
#pragma unroll
      for (int d = 0; d < 4; ++d)
        lds[(hg * 4 + d) * 68 + k * 16 + rB] = q[k * 4 + d];
    __syncthreads();
    float s[16];
#pragma unroll
    for (int j = 0; j < 16; ++j) s[j] = lds[(4 * j + rr) * 68 + wC];
    bfly16<1>(s); bfly16<2>(s); bfly16<4>(s); bfly16<8>(s);
    if (wC < 56) {
      const size_t plane = (size_t)(b * 128 + og * 8 + pp) * 3136;
#pragma unroll
      for (int j = 0; j < 14; ++j) {  // h = 4j+rr <= 55
        const int h = 4 * j + rr;
        const size_t idx = plane + (size_t)(h * 56 + wC);
        y[idx] = x[idx] + s[j] * (1.f / 4096.f);
      }
    }
  }
}

extern "C" void kernel_launch(void* const* d_in, const int* in_sizes, int n_in,
                              void* d_out, int out_size, void* d_ws, size_t ws_size,
                              hipStream_t stream) {
  const float* x = (const float*)d_in[0];
  const float* cw = (const float*)d_in[1];
  const float* v = (const float*)d_in[2];
  const float* T = (const float*)d_in[3];
  float* y = (float*)d_out;

  u16* f2 = (u16*)d_ws;                        // 64*16*4096*8 bf16 = 67,108,864 B
  u16* wcat = (u16*)((char*)d_ws + 67108864);  // 2*128*128 bf16 = 65,536 B

  k0_wcat<<<128, 256, 0, stream>>>(cw, wcat);
  k1_fwht<<<1024, 256, 0, stream>>>(x, f2);
  k2_mix<<<4096, 256, 0, stream>>>(f2, wcat, v, T);
  k3_iwht<<<1024, 256, 0, stream>>>(f2, x, y);
}